// Round 4
// baseline (85.660 us; speedup 1.0000x reference)
//
#include <hip/hip_runtime.h>

// PointSample: bilinear grid sample, zero border.
// features: (8,128,128,256) f32, grid: (8,16384,2) f32, out: (8,16384,256) f32.
// 4 points per 64-lane wave; lane owns 4 channels (float4).
// Grid coords fetched via scalar loads (uniform address); all 16 corner
// loads issued unconditionally (clamped index, zero weight for OOB) to
// maximize memory-level parallelism. NT stores for the write-once output.

constexpr int B = 8, H = 128, W = 128, C = 256, P = 16384;
constexpr int PPW = 4;  // points per wave

typedef float f32x4 __attribute__((ext_vector_type(4)));

__global__ __launch_bounds__(256) void point_sample_kernel(
    const float* __restrict__ features,
    const float* __restrict__ grid,
    float* __restrict__ out)
{
    const int wave = threadIdx.x >> 6;        // 4 waves per block
    const int lane = threadIdx.x & 63;
    int pt0 = (blockIdx.x * 4 + wave) * PPW;  // first point of this wave
    pt0 = __builtin_amdgcn_readfirstlane(pt0);
    const int b = pt0 >> 14;                  // P = 16384, PPW divides P
    const float* fb = features + (size_t)b * H * W * C;
    const int c = lane * 4;                   // 4 channels per lane

    // 4 points x float2 = 32 B, contiguous, uniform address -> s_load
    const float4* gp = reinterpret_cast<const float4*>(grid + (size_t)pt0 * 2);
    const float4 gA = gp[0];                  // x0,y0,x1,y1
    const float4 gB = gp[1];                  // x2,y2,x3,y3
    const float gxv[PPW] = {gA.x, gA.z, gB.x, gB.z};
    const float gyv[PPW] = {gA.y, gA.w, gB.y, gB.w};

    int   off[PPW][4];
    float wgt[PPW][4];
    #pragma unroll
    for (int k = 0; k < PPW; ++k) {
        const float x = gxv[k] * (float)W - 0.5f;
        const float y = gyv[k] * (float)H - 0.5f;
        const float fx = floorf(x), fy = floorf(y);
        const int ix = (int)fx, iy = (int)fy;
        const float frx = x - fx, fry = y - fy;

        const int x0 = min(max(ix, 0), W - 1);
        const int x1 = min(max(ix + 1, 0), W - 1);
        const int y0 = min(max(iy, 0), H - 1);
        const int y1 = min(max(iy + 1, 0), H - 1);
        const float mx0 = (ix >= 0 && ix < W)         ? 1.f : 0.f;
        const float mx1 = (ix + 1 >= 0 && ix + 1 < W) ? 1.f : 0.f;
        const float my0 = (iy >= 0 && iy < H)         ? 1.f : 0.f;
        const float my1 = (iy + 1 >= 0 && iy + 1 < H) ? 1.f : 0.f;

        wgt[k][0] = (1.f - fry) * (1.f - frx) * my0 * mx0;  // (y0,x0)
        wgt[k][1] = (1.f - fry) * frx         * my0 * mx1;  // (y0,x1)
        wgt[k][2] = fry         * (1.f - frx) * my1 * mx0;  // (y1,x0)
        wgt[k][3] = fry         * frx         * my1 * mx1;  // (y1,x1)
        off[k][0] = (y0 * W + x0) * C + c;
        off[k][1] = (y0 * W + x1) * C + c;
        off[k][2] = (y1 * W + x0) * C + c;
        off[k][3] = (y1 * W + x1) * C + c;
    }

    // Issue all 16 independent 1 KiB loads before consuming.
    float4 v[PPW][4];
    #pragma unroll
    for (int k = 0; k < PPW; ++k)
        #pragma unroll
        for (int j = 0; j < 4; ++j)
            v[k][j] = *reinterpret_cast<const float4*>(fb + off[k][j]);

    #pragma unroll
    for (int k = 0; k < PPW; ++k) {
        f32x4 acc = (f32x4)0.f;
        #pragma unroll
        for (int j = 0; j < 4; ++j) {
            const float wq = wgt[k][j];
            acc.x += wq * v[k][j].x;
            acc.y += wq * v[k][j].y;
            acc.z += wq * v[k][j].z;
            acc.w += wq * v[k][j].w;
        }
        f32x4* op = reinterpret_cast<f32x4*>(out + (size_t)(pt0 + k) * C + c);
        __builtin_nontemporal_store(acc, op);
    }
}

extern "C" void kernel_launch(void* const* d_in, const int* in_sizes, int n_in,
                              void* d_out, int out_size, void* d_ws, size_t ws_size,
                              hipStream_t stream) {
    const float* features = (const float*)d_in[0];
    const float* grid     = (const float*)d_in[1];
    float* out            = (float*)d_out;

    const int n_points = B * P;               // 131072
    dim3 block(256);
    dim3 grd(n_points / (4 * PPW));           // 16 points per block
    point_sample_kernel<<<grd, block, 0, stream>>>(features, grid, out);
}